// Round 1
// 109.846 us; speedup vs baseline: 1.0939x; 1.0939x over previous
//
#include <hip/hip_runtime.h>

#define N_NODES 200000
#define C 256
#define VC 16
#define VD 3
#define VDIM (VC * VD)   // 48
#define M_MOTIFS 50000
#define CAP 64           // per-motif slot capacity; Poisson(4) => P(count>64) ~ 1e-36

#define TM 64            // motifs per fused block
#define NODE_BLOCKS ((N_NODES + 255) / 256)       // 782
#define CVT_BLOCKS  ((C * C) / (256 * 4))         // 64 (float4 per thread)
#define FUSED_BLOCKS ((M_MOTIFS + TM - 1) / TM)   // 782

typedef __attribute__((ext_vector_type(8))) __bf16 bf16x8;
typedef __attribute__((ext_vector_type(4))) float f32x4;

__device__ __forceinline__ unsigned short f2bf(float x) {
  unsigned u = __builtin_bit_cast(unsigned, x);
  u += 0x7fffu + ((u >> 16) & 1u);   // RNE
  return (unsigned short)(u >> 16);
}

// ---------------------------------------------------------------------------
// K1: slot-fill. rank = atomicAdd(cnt[m]); nodelist[m*64+rank] = i.
//     Replaces count + 3 scan kernels + place. Extra blocks convert Ws->bf16.
// ---------------------------------------------------------------------------
__global__ __launch_bounds__(256) void fill_kernel(
    const int* __restrict__ seg, int* __restrict__ cnt,
    int* __restrict__ nodelist, const float* __restrict__ Ws,
    unsigned short* __restrict__ Wsb) {
  int b = blockIdx.x, t = threadIdx.x;
  if (b < NODE_BLOCKS) {
    int i = b * 256 + t;
    if (i < N_NODES) {
      int m = seg[i];
      int r = atomicAdd(&cnt[m], 1);
      if (r < CAP) nodelist[(size_t)m * CAP + r] = i;
    }
  } else {
    int i = ((b - NODE_BLOCKS) * 256 + t) * 4;
    float4 w = *(const float4*)(Ws + i);
    ushort4 o;
    o.x = f2bf(w.x); o.y = f2bf(w.y); o.z = f2bf(w.z); o.w = f2bf(w.w);
    *(ushort4*)(Wsb + i) = o;
  }
}

// ---------------------------------------------------------------------------
// K2: fused gather-mean + v-linear + bf16 MFMA GEMM.
//     Block = 64 motifs x all 256 output cols, 4 waves.
//     Phase 1: wave w gathers motifs [w*16, w*16+16): metadata (cnt + first 8
//       node ids) preloaded in 3 coalesced gathers, s-rows loaded float4/lane
//       4-way unrolled, mean -> bf16 -> XOR-swizzled LDS A row. v 16x16 linear
//       fused via shuffles -> v_out directly.
//     Phase 2: 1 syncthreads, then wave w computes cols [w*64, w*64+64):
//       A fragments from swizzled LDS (conflict-free ds_read_b128), B
//       fragments straight from L2-resident Wsb (128 KB total, no staging).
// ---------------------------------------------------------------------------
__global__ __launch_bounds__(256, 3) void fused_kernel(
    const float* __restrict__ s, const float* __restrict__ v,
    const int* __restrict__ cnt, const int* __restrict__ nodelist,
    const unsigned short* __restrict__ Wsb, const float* __restrict__ bs,
    const float* __restrict__ Wv, const float* __restrict__ bv,
    float* __restrict__ s_out, float* __restrict__ v_out) {
  __shared__ unsigned short As[TM * C];   // 32 KB, rows XOR-swizzled by (row&7)<<3

  int tid = threadIdx.x;
  int wave = tid >> 6, lane = tid & 63;
  int bm0 = blockIdx.x * TM;
  int m0w = bm0 + wave * 16;

  // ---- phase 1: gather ----
  int kv = 0;
  if (lane < 16) {
    int mm = m0w + lane;
    if (mm < M_MOTIFS) kv = cnt[mm];
  }
  // first 8 node ids of each of the 16 motifs, two coalesced gathers
  int rA = lane >> 3, sl = lane & 7;
  int kA = __shfl(kv, rA, 64);
  int kB = __shfl(kv, 8 + rA, 64);
  int id8a = 0, id8b = 0;
  if (sl < kA) id8a = nodelist[(size_t)(m0w + rA) * CAP + sl];
  if (sl < kB) id8b = nodelist[(size_t)(m0w + 8 + rA) * CAP + sl];

  for (int r = 0; r < 16; ++r) {
    int m = m0w + r;
    int k = __shfl(kv, r, 64);
    int idr = (r < 8) ? id8a : id8b;
    int rb = (r & 7) * 8;
    float4 acc = make_float4(0.f, 0.f, 0.f, 0.f);
    float vacc = 0.f;
    int kc = min(k, CAP);
    int n8 = min(kc, 8);
    int jj = 0;
    for (; jj + 4 <= n8; jj += 4) {
      int i0 = __shfl(idr, rb + jj + 0, 64);
      int i1 = __shfl(idr, rb + jj + 1, 64);
      int i2 = __shfl(idr, rb + jj + 2, 64);
      int i3 = __shfl(idr, rb + jj + 3, 64);
      float4 a = ((const float4*)(s + (size_t)i0 * C))[lane];
      float4 b = ((const float4*)(s + (size_t)i1 * C))[lane];
      float4 c = ((const float4*)(s + (size_t)i2 * C))[lane];
      float4 d = ((const float4*)(s + (size_t)i3 * C))[lane];
      acc.x += (a.x + b.x) + (c.x + d.x);
      acc.y += (a.y + b.y) + (c.y + d.y);
      acc.z += (a.z + b.z) + (c.z + d.z);
      acc.w += (a.w + b.w) + (c.w + d.w);
      if (lane < VDIM) {
        float va = v[(size_t)i0 * VDIM + lane];
        float vb = v[(size_t)i1 * VDIM + lane];
        float vc = v[(size_t)i2 * VDIM + lane];
        float vd = v[(size_t)i3 * VDIM + lane];
        vacc += (va + vb) + (vc + vd);
      }
    }
    for (; jj < n8; ++jj) {
      int i0 = __shfl(idr, rb + jj, 64);
      float4 a = ((const float4*)(s + (size_t)i0 * C))[lane];
      acc.x += a.x; acc.y += a.y; acc.z += a.z; acc.w += a.w;
      if (lane < VDIM) vacc += v[(size_t)i0 * VDIM + lane];
    }
    if (kc > 8) {  // ~2% of motifs (Poisson(4), P(k>8)~2%)
      int nid2 = 0;
      if (lane >= 8 && lane < kc) nid2 = nodelist[(size_t)m * CAP + lane];
      for (int j = 8; j < kc; ++j) {
        int i0 = __shfl(nid2, j, 64);
        float4 a = ((const float4*)(s + (size_t)i0 * C))[lane];
        acc.x += a.x; acc.y += a.y; acc.z += a.z; acc.w += a.w;
        if (lane < VDIM) vacc += v[(size_t)i0 * VDIM + lane];
      }
    }

    float rc = 1.0f / (float)max(k, 1);
    ushort4 o;
    o.x = f2bf(acc.x * rc); o.y = f2bf(acc.y * rc);
    o.z = f2bf(acc.z * rc); o.w = f2bf(acc.w * rc);
    int rblk = wave * 16 + r;
    *(ushort4*)&As[rblk * C + ((lane * 4) ^ ((rblk & 7) << 3))] = o;

    float vm = vacc * rc;   // lane c*3+d holds vmean[c][d]
    if (lane < VDIM && m < M_MOTIFS) {
      int oo = lane / 3, d = lane - oo * 3;
      float vo = bv[oo];
#pragma unroll
      for (int c = 0; c < VC; ++c)
        vo += Wv[oo * VC + c] * __shfl(vm, c * 3 + d, 64);
      v_out[(size_t)m * VDIM + lane] = vo;
    }
  }

  __syncthreads();

  // ---- phase 2: GEMM. wave covers all 64 rows x its 64-col strip ----
  int rl = lane & 15, kq = (lane >> 4) * 8;
  int wn0 = wave * 64;
  int xorv = (rl & 7) << 3;          // read-side swizzle (row&7 == rl&7)
  f32x4 acc4[4][4] = {};
  for (int k0 = 0; k0 < C; k0 += 32) {
    bf16x8 af[4], bfr[4];
#pragma unroll
    for (int i = 0; i < 4; ++i)
      af[i] = *(const bf16x8*)&As[(i * 16 + rl) * C + ((k0 + kq) ^ xorv)];
#pragma unroll
    for (int j = 0; j < 4; ++j)
      bfr[j] = *(const bf16x8*)(Wsb + (size_t)(wn0 + j * 16 + rl) * C + k0 + kq);
#pragma unroll
    for (int i = 0; i < 4; ++i)
#pragma unroll
      for (int j = 0; j < 4; ++j)
        acc4[i][j] = __builtin_amdgcn_mfma_f32_16x16x32_bf16(
            af[i], bfr[j], acc4[i][j], 0, 0, 0);
  }

  int rq = (lane >> 4) * 4;
#pragma unroll
  for (int j = 0; j < 4; ++j) {
    int cn = wn0 + j * 16 + rl;
    float bias = bs[cn];
#pragma unroll
    for (int i = 0; i < 4; ++i) {
#pragma unroll
      for (int rr = 0; rr < 4; ++rr) {
        int gm = bm0 + i * 16 + rq + rr;
        if (gm < M_MOTIFS) s_out[(size_t)gm * C + cn] = acc4[i][j][rr] + bias;
      }
    }
  }
}

extern "C" void kernel_launch(void* const* d_in, const int* in_sizes, int n_in,
                              void* d_out, int out_size, void* d_ws, size_t ws_size,
                              hipStream_t stream) {
  const float* s  = (const float*)d_in[0];
  const float* v  = (const float*)d_in[1];
  const int*   seg = (const int*)d_in[2];
  const float* Ws = (const float*)d_in[3];
  const float* bs = (const float*)d_in[4];
  const float* Wv = (const float*)d_in[5];
  const float* bv = (const float*)d_in[6];

  float* out   = (float*)d_out;
  float* s_out = out;
  float* v_out = out + (size_t)M_MOTIFS * C;

  // ws layout (~13.1 MB): [cnt M][nodelist M*CAP][Wsb C*C bf16]
  int* cnt      = (int*)d_ws;
  int* nodelist = cnt + M_MOTIFS;
  unsigned short* Wsb = (unsigned short*)(nodelist + (size_t)M_MOTIFS * CAP);
  // Wsb byte offset = 800000 + 12800000 = 13600000, 16B-aligned.

  hipMemsetAsync(cnt, 0, M_MOTIFS * sizeof(int), stream);
  fill_kernel<<<NODE_BLOCKS + CVT_BLOCKS, 256, 0, stream>>>(seg, cnt, nodelist,
                                                            Ws, Wsb);
  fused_kernel<<<FUSED_BLOCKS, 256, 0, stream>>>(s, v, cnt, nodelist, Wsb, bs,
                                                 Wv, bv, s_out, v_out);
}